// Round 12
// baseline (2477.543 us; speedup 1.0000x reference)
//
#include <hip/hip_runtime.h>
#include <stdint.h>

#define NPTS   32768
#define NBATCH 8
#define NFPS   512
#define NGRP   32
#define BIGF   1e10f
#define R2F    0.04f
#define CAP    512
#define QPB    4      // ball-query centroids per block

// FPS decomposition
#define P      8                  // blocks per batch
#define PPB    (NPTS / P)         // 4096 points per block
#define CHUNKS (PPB / 4)          // 1024 float4-chunks per block
#define THR    512                // threads per fps block
#define CPT    (CHUNKS / THR)     // 2 chunks (8 points) per thread
#define SLOTB  32                 // bytes per mail slot
#define FROUNDS 24                // sc0 (local-L2) poll rounds before sc1

typedef unsigned long long u64;
typedef unsigned int v4u __attribute__((ext_vector_type(4)));
typedef unsigned int v2u __attribute__((ext_vector_type(2)));

__device__ __forceinline__ u64 shfl_xor_u64(u64 v, int off) {
    unsigned lo = (unsigned)v, hi = (unsigned)(v >> 32);
    lo = __shfl_xor(lo, off, 64);
    hi = __shfl_xor(hi, off, 64);
    return ((u64)hi << 32) | lo;
}

// Message A (16B, one transaction): [w0=(it<<15)|(0x7FFF-idx), w1=distbits,
// w2=x, w3=y]; Message B (8B): [w0=A.w0, w1=z]. Valid iff A.x>>15==it,
// B.x==A.x, distbits MSB==0. Slots are NFPS-indexed and write-once, so the
// tag rejects 0xAA poison (tag 0x15555>510), zeros, and any pre-kernel
// garbage; prior-replay data is bit-identical -> benign (R7-R11, absmax 0).
// Tag bits sit above idx and all compared entries share a tag, so u64 key
// ordering (max dist, ties -> min idx) is unaffected.
//
// R12 store discipline: PLAIN store first -- CDNA vector L1 is
// write-through, so it lands in the local XCD L2 fast, where same-XCD sc0
// pollers (L1-bypass, L2-read) see it in ~250 cyc. Then a duplicate
// sc0+sc1 store publishes to the device coherence point so cross-XCD
// readers (sc1 fallback after FROUNDS) stay correct under ANY placement.
__device__ __forceinline__ void mail_store(u64 addr, v4u A, v2u B) {
    asm volatile(
        "global_store_dwordx4 %0, %2, off\n\t"
        "global_store_dwordx2 %1, %3, off\n\t"
        "global_store_dwordx4 %0, %2, off sc0 sc1\n\t"
        "global_store_dwordx2 %1, %3, off sc0 sc1"
        :: "v"(addr), "v"(addr + 16), "v"(A), "v"(B) : "memory");
}
__device__ __forceinline__ void mail_loadF(u64 addr, v4u* A, v2u* B) {
    asm volatile(      // sc0: bypass L1, read local XCD L2 (fast path)
        "global_load_dwordx4 %0, %2, off sc0\n\t"
        "global_load_dwordx2 %1, %3, off sc0\n\t"
        "s_waitcnt vmcnt(0)"
        : "=v"(*A), "=v"(*B) : "v"(addr), "v"(addr + 16) : "memory");
}
__device__ __forceinline__ void mail_loadS(u64 addr, v4u* A, v2u* B) {
    asm volatile(      // sc0 sc1: device coherence point (always correct)
        "global_load_dwordx4 %0, %2, off sc0 sc1\n\t"
        "global_load_dwordx2 %1, %3, off sc0 sc1\n\t"
        "s_waitcnt vmcnt(0)"
        : "=v"(*A), "=v"(*B) : "v"(addr), "v"(addr + 16) : "memory");
}

// ---------------------------------------------------------------------------
// FPS: P=8 blocks/batch (b=gb&7 -> all 8 on one XCD under the measured
// round-robin map), points in LDS (48 KB, thread-owned), dist[8] in VGPRs.
// R12: ONE barrier/iter. Waves write redK, barrier, wave0 reduces + posts
// the block candidate; ALL waves then poll the 8 slots themselves (lanes
// 0-7, coalesced 24 B, sc0 rounds then sc1) and reduce the winner
// in-register -- barrier2/farbox deleted. redK single-buffer is safe: any
// wave's redK write for it+1 happens after it passed poll(it), which
// requires wave0's post(it), which is after wave0's redK reads(it).
// Poll population: 64 waves/batch on 2 cache lines of local L2 (~3 orders
// below R11's storm; R11 regressed via 64-slot all-wave polling).
// Distance math bit-exact vs reference: contract off, (dx^2+dy^2)+dz^2,
// fminf accumulate; per-thread strict '>' in ascending global order keeps
// first occurrence; key (distbits<<32 | tag|(0x7FFF-idx)).
// ---------------------------------------------------------------------------
__global__ __launch_bounds__(THR) void fps_kernel(
    const float* __restrict__ xyz,
    const int* __restrict__ finit,
    int* __restrict__ cidx,        // [NBATCH][NFPS]
    u64 mailAddr)                  // mail[NFPS-1][NBATCH][P] slots of 32 B
{
#pragma clang fp contract(off)
    const int gb = blockIdx.x;
    const int b  = gb & 7;         // batch (gb%8 -> same XCD per batch)
    const int me = gb >> 3;        // sub-block within batch
    const int t  = threadIdx.x;
    const float* __restrict__ base = xyz + (size_t)b * (NPTS * 3);

    __shared__ float4 xs4[CHUNKS], ys4[CHUNKS], zs4[CHUNKS];   // 48 KB
    __shared__ u64 redK[8];

    // ---- transpose own points into LDS; every element is written and read
    // by the SAME thread -> no publication barrier needed ----
    float dist[4 * CPT];
#pragma unroll
    for (int j = 0; j < CPT; ++j) {
        const int c = t + j * THR;
        const float4* __restrict__ g4 =
            reinterpret_cast<const float4*>(base) + 3 * (me * CHUNKS + c);
        const float4 q0 = g4[0];
        const float4 q1 = g4[1];
        const float4 q2 = g4[2];
        xs4[c] = make_float4(q0.x, q0.w, q1.z, q2.y);
        ys4[c] = make_float4(q0.y, q1.x, q1.w, q2.z);
        zs4[c] = make_float4(q0.z, q1.y, q2.x, q2.w);
        dist[4 * j + 0] = BIGF; dist[4 * j + 1] = BIGF;
        dist[4 * j + 2] = BIGF; dist[4 * j + 3] = BIGF;
    }

    int far = finit[b];
    float cx = base[3 * far + 0];
    float cy = base[3 * far + 1];
    float cz = base[3 * far + 2];

    const int wid  = t >> 6;       // 0..7
    const int lane = t & 63;

    for (int it = 0; it < NFPS; ++it) {
        if (me == 0 && t == 0) cidx[b * NFPS + it] = far;  // record BEFORE update
        if (it == NFPS - 1) break;                          // last far never used

        float vmax = -1.0f;
        int   amax = 0;

#define PROC(K, PX, PY, PZ, GI)                               \
        {                                                     \
            float dx = (PX) - cx;                             \
            float dy = (PY) - cy;                             \
            float dz = (PZ) - cz;                             \
            float d  = dx * dx + dy * dy;                     \
            d = d + dz * dz;                                  \
            float dk = fminf(dist[K], d);                     \
            dist[K] = dk;                                     \
            if (dk > vmax) { vmax = dk; amax = (GI); }        \
        }

#pragma unroll
        for (int j = 0; j < CPT; ++j) {
            const int c  = t + j * THR;
            const float4 xv = xs4[c];
            const float4 yv = ys4[c];
            const float4 zv = zs4[c];
            const int gi = me * PPB + 4 * c;
            PROC(4 * j + 0, xv.x, yv.x, zv.x, gi + 0);
            PROC(4 * j + 1, xv.y, yv.y, zv.y, gi + 1);
            PROC(4 * j + 2, xv.z, yv.z, zv.z, gi + 2);
            PROC(4 * j + 3, xv.w, yv.w, zv.w, gi + 3);
        }
#undef PROC

        // wave key: distbits<<32 | (it<<15 | (0x7FFF-idx))
        const unsigned low = ((unsigned)it << 15) | (unsigned)(0x7FFF - amax);
        u64 key = ((u64)__float_as_uint(vmax) << 32) | low;
#pragma unroll
        for (int off = 32; off >= 1; off >>= 1) {
            u64 o = shfl_xor_u64(key, off);
            key = (o > key) ? o : key;
        }
        if (lane == 0) redK[wid] = key;
        __syncthreads();               // the ONE barrier per iteration

        const u64 rowAddr = mailAddr + (u64)((it * NBATCH + b) * P) * SLOTB;

        if (wid == 0) {
            u64 blockKey = redK[0];
#pragma unroll
            for (int w = 1; w < 8; ++w) {
                u64 o = redK[w];
                blockKey = (o > blockKey) ? o : blockKey;
            }
            const int gidx = 0x7FFF - (int)(blockKey & 0x7FFF);
            const int li   = gidx - me * PPB;           // in [0, PPB)
            if (lane == 0) {
                v4u A; v2u B;
                A.x = (unsigned)(blockKey & 0xFFFFFFFFull);
                A.y = (unsigned)(blockKey >> 32);
                A.z = __float_as_uint(reinterpret_cast<const float*>(xs4)[li]);
                A.w = __float_as_uint(reinterpret_cast<const float*>(ys4)[li]);
                B.x = A.x;
                B.y = __float_as_uint(reinterpret_cast<const float*>(zs4)[li]);
                mail_store(rowAddr + (u64)me * SLOTB, A, B);
            }
        }

        // every wave polls the 8 block-slots itself: lane L (<8) owns slot L
        v4u A; v2u B;
        bool have = (lane >= P);
        const u64 myAddr = rowAddr + (u64)(lane & 7) * SLOTB;
        int round = 0;
        for (;;) {
            if (!have) {
                if (round < FROUNDS) mail_loadF(myAddr, &A, &B);
                else                 mail_loadS(myAddr, &A, &B);
                have = ((A.x >> 15) == (unsigned)it)
                     && (B.x == A.x)
                     && ((A.y >> 31) == 0);
            }
            ++round;
            if (__all(have ? 1 : 0)) break;
        }

        // winner reduce over lanes 0..7 (xor-closed; lanes >=8 hold k=0)
        u64   k  = (lane < P) ? (((u64)A.y << 32) | A.x) : 0ull;
        float px = __uint_as_float(A.z);
        float py = __uint_as_float(A.w);
        float pz = __uint_as_float(B.y);
#pragma unroll
        for (int off = 4; off >= 1; off >>= 1) {
            const u64   ok = shfl_xor_u64(k, off);
            const float ox = __shfl_xor(px, off, 64);
            const float oy = __shfl_xor(py, off, 64);
            const float oz = __shfl_xor(pz, off, 64);
            if (ok > k) { k = ok; px = ox; py = oy; pz = oz; }
        }
        const int fv = 0x7FFF - (int)(k & 0x7FFF);
        far = __shfl(fv, 0, 64);
        cx  = __shfl(px, 0, 64);
        cy  = __shfl(py, 0, 64);
        cz  = __shfl(pz, 0, 64);
    }
}

// ---------------------------------------------------------------------------
// Ball query + grouping: QPB centroids per block (unchanged from R8-R11).
// ---------------------------------------------------------------------------
__global__ __launch_bounds__(256) void ballq_kernel(
    const float* __restrict__ xyz,
    const int* __restrict__ cidx,
    float* __restrict__ out0,      // [B][S][33][3]
    float* __restrict__ out1)      // [B][S][3]
{
#pragma clang fp contract(off)
    const int blk0 = blockIdx.x * QPB;   // first global centroid (b*NFPS+s)
    const int b    = blk0 >> 9;          // QPB divides NFPS -> same batch
    const int t    = threadIdx.x;
    const float* __restrict__ base = xyz + (size_t)b * (NPTS * 3);

    __shared__ u64 list[QPB][CAP];
    __shared__ int scnt[QPB];
    __shared__ u64 mask0[QPB];
    __shared__ int selIdx[QPB][NGRP];

    if (t < QPB) scnt[t] = 0;

    float cxs[QPB], cys[QPB], czs[QPB];
#pragma unroll
    for (int q = 0; q < QPB; ++q) {
        const int ci = cidx[blk0 + q];
        cxs[q] = base[3 * ci + 0];
        cys[q] = base[3 * ci + 1];
        czs[q] = base[3 * ci + 2];
    }
    __syncthreads();

    // in-ball masks for the first 64 indices (fill candidates); wave 0 only
    if (t < 64) {
        const float px = base[3 * t + 0];
        const float py = base[3 * t + 1];
        const float pz = base[3 * t + 2];
#pragma unroll
        for (int q = 0; q < QPB; ++q) {
            float dx = px - cxs[q];
            float dy = py - cys[q];
            float dz = pz - czs[q];
            float d  = dx * dx + dy * dy;
            d = d + dz * dz;
            u64 mk = __ballot(d <= R2F);
            if (t == 0) mask0[q] = mk;
        }
    }

    // scan all points once; test against all QPB centroids
    for (int k = 0; k < NPTS / 256; ++k) {
        const int p = k * 256 + t;
        const float px = base[3 * p + 0];
        const float py = base[3 * p + 1];
        const float pz = base[3 * p + 2];
#pragma unroll
        for (int q = 0; q < QPB; ++q) {
            float dx = px - cxs[q];
            float dy = py - cys[q];
            float dz = pz - czs[q];
            float d  = dx * dx + dy * dy;
            d = d + dz * dz;
            if (d <= R2F) {
                int pos = atomicAdd(&scnt[q], 1);
                if (pos < CAP)
                    list[q][pos] = (((u64)__float_as_uint(d)) << 32)
                                   | (unsigned)p;
            }
        }
    }
    __syncthreads();

    // rank-based selection, one wave per centroid:
    // key's rank == #smaller keys (keys unique via idx)
    {
        const int q    = t >> 6;     // wave id 0..3
        const int lane = t & 63;
        const int m = min(scnt[q], CAP);
        for (int j = lane; j < m; j += 64) {
            const u64 kj = list[q][j];
            int rank = 0;
            for (int i = 0; i < m; ++i) rank += (list[q][i] < kj) ? 1 : 0;
            if (rank < NGRP) selIdx[q][rank] = (int)(kj & 0xffffffffu);
        }
    }
    __syncthreads();

    if (t < 33 * QPB) {
        const int q    = t / 33;
        const int slot = t % 33;
        const int sg   = blk0 + q;
        const float cx = cxs[q], cy = cys[q], cz = czs[q];
        const size_t o0 = (size_t)sg * 33 * 3;
        if (slot == 32) {
            out0[o0 + 0] = cx; out0[o0 + 1] = cy; out0[o0 + 2] = cz;
            const size_t o1 = (size_t)sg * 3;
            out1[o1 + 0] = cx; out1[o1 + 1] = cy; out1[o1 + 2] = cz;
        } else {
            const int m = min(scnt[q], CAP);
            const int K = min(m, NGRP);
            int idx;
            if (slot < K) {
                idx = selIdx[q][slot];
            } else {
                // (slot-K+1)-th zero bit of mask0 = next out-of-radius index
                u64 zeros = ~mask0[q];
                const int need = slot - K;
                for (int z = 0; z < need; ++z) zeros &= zeros - 1;
                idx = __builtin_ctzll(zeros);
            }
            const float px = base[3 * idx + 0];
            const float py = base[3 * idx + 1];
            const float pz = base[3 * idx + 2];
            out0[o0 + (size_t)(1 + slot) * 3 + 0] = px - cx;
            out0[o0 + (size_t)(1 + slot) * 3 + 1] = py - cy;
            out0[o0 + (size_t)(1 + slot) * 3 + 2] = pz - cz;
        }
    }
}

extern "C" void kernel_launch(void* const* d_in, const int* in_sizes, int n_in,
                              void* d_out, int out_size, void* d_ws, size_t ws_size,
                              hipStream_t stream) {
    const float* xyz   = (const float*)d_in[0];
    const int*   finit = (const int*)d_in[1];
    float* out0 = (float*)d_out;
    float* out1 = out0 + (size_t)NBATCH * NFPS * 33 * 3;

    // ws layout: cidx 16 KB | mail (NFPS-1)*8*8*32 B = 1.0465 MB
    // total 1.0628 MB <= proven available (R9 used this exact layout).
    int* cidx = (int*)d_ws;
    u64  mailAddr = (u64)(uintptr_t)((char*)d_ws
                   + (size_t)NBATCH * NFPS * sizeof(int));

    fps_kernel<<<NBATCH * P, THR, 0, stream>>>(xyz, finit, cidx, mailAddr);
    ballq_kernel<<<(NBATCH * NFPS) / QPB, 256, 0, stream>>>(xyz, cidx, out0, out1);
}

// Round 13
// 1682.584 us; speedup vs baseline: 1.4725x; 1.4725x over previous
//
#include <hip/hip_runtime.h>
#include <stdint.h>

#define NPTS   32768
#define NBATCH 8
#define NFPS   512
#define NGRP   32
#define BIGF   1e10f
#define R2F    0.04f
#define CAP    512
#define QPB    4      // ball-query centroids per block

// FPS decomposition
#define P      8                  // blocks per batch
#define PPB    (NPTS / P)         // 4096 points per block
#define CHUNKS (PPB / 4)          // 1024 float4-chunks per block
#define THR    512                // threads per fps block
#define CPT    (CHUNKS / THR)     // 2 chunks (8 points) per thread
#define SLOTB  32                 // bytes per mail slot
#define FROUNDS 16                // sc0 (local-L2) poll rounds before sc1

typedef unsigned long long u64;
typedef unsigned int v4u __attribute__((ext_vector_type(4)));
typedef unsigned int v2u __attribute__((ext_vector_type(2)));

__device__ __forceinline__ u64 shfl_xor_u64(u64 v, int off) {
    unsigned lo = (unsigned)v, hi = (unsigned)(v >> 32);
    lo = __shfl_xor(lo, off, 64);
    hi = __shfl_xor(hi, off, 64);
    return ((u64)hi << 32) | lo;
}

// Message A (16B, one transaction): [w0=~idx, w1=distbits, w2=x, w3=y]
// Message B ( 8B, one transaction): [w0=A.w0, w1=z]
// Valid iff distbits MSB==0, ~idx in [0xFFFF8000,0xFFFFFFFF] (idx<32768),
// B.x==A.x. Rejects 0xAA poison, zeros, torn A-new/B-old (write-once slots).
// Prior-replay values are bit-identical -> benign (R7-R12, absmax 0.0).
__device__ __forceinline__ bool msg_valid(v4u A, v2u B) {
    return ((A.y >> 31) == 0) && (A.x >= 0xFFFF8000u) && (B.x == A.x);
}

// R13 store discipline (the ONE change vs R10): PLAIN store first -- the
// vector L1 is write-through, so it lands in the LOCAL XCD L2, where
// same-XCD sc0 pollers (L1-bypass, L2-read) can hit in ~250 cyc instead of
// the ~900 cyc device-coherence round trip. The duplicate sc0+sc1 store
// publishes to the L3 coherence point so the sc1 fallback stays correct
// under ANY block placement (hang-free regardless of the XCD map).
__device__ __forceinline__ void mail_store(u64 addr, v4u A, v2u B) {
    asm volatile(
        "global_store_dwordx4 %0, %2, off\n\t"
        "global_store_dwordx2 %1, %3, off\n\t"
        "global_store_dwordx4 %0, %2, off sc0 sc1\n\t"
        "global_store_dwordx2 %1, %3, off sc0 sc1"
        :: "v"(addr), "v"(addr + 16), "v"(A), "v"(B) : "memory");
}
__device__ __forceinline__ void mail_loadF(u64 addr, v4u* A, v2u* B) {
    asm volatile(      // sc0: bypass L1, read the local XCD L2 (fast path)
        "global_load_dwordx4 %0, %2, off sc0\n\t"
        "global_load_dwordx2 %1, %3, off sc0\n\t"
        "s_waitcnt vmcnt(0)"
        : "=v"(*A), "=v"(*B) : "v"(addr), "v"(addr + 16) : "memory");
}
__device__ __forceinline__ void mail_loadS(u64 addr, v4u* A, v2u* B) {
    asm volatile(      // sc0 sc1: device coherence point (always correct)
        "global_load_dwordx4 %0, %2, off sc0 sc1\n\t"
        "global_load_dwordx2 %1, %3, off sc0 sc1\n\t"
        "s_waitcnt vmcnt(0)"
        : "=v"(*A), "=v"(*B) : "v"(addr), "v"(addr + 16) : "memory");
}

// ---------------------------------------------------------------------------
// FPS: P=8 blocks per batch (b=gb&7 -> all 8 on one XCD under the measured
// round-robin map), points in LDS (48 KB, thread-owned), dist[8] in VGPRs.
// Structure = R10 exactly (best known: 2.57us/iter): 2 barriers/iter, wave0
// does the whole exchange (posting + lane-parallel poll of 8 slots + winner
// reduce), winner broadcast via LDS boxes. R12's lesson: all-wave polling
// without barrier2 lets fast waves steal SIMD issue slots from wave0 and
// convoy the posts -- keep wave0's critical path unloaded.
// Distance math bit-exact vs reference: contract off, (dx^2+dy^2)+dz^2,
// fminf accumulate; key (distbits<<32 | ~idx): max dist, ties -> min index;
// per-thread strict '>' in ascending global order keeps first occurrence.
// ---------------------------------------------------------------------------
__global__ __launch_bounds__(THR) void fps_kernel(
    const float* __restrict__ xyz,
    const int* __restrict__ finit,
    int* __restrict__ cidx,        // [NBATCH][NFPS]
    u64 mailAddr)                  // mail[NFPS-1][NBATCH][P] slots of 32 B
{
#pragma clang fp contract(off)
    const int gb = blockIdx.x;
    const int b  = gb & 7;         // batch (gb%8 -> same XCD per batch)
    const int me = gb >> 3;        // sub-block within batch
    const int t  = threadIdx.x;
    const float* __restrict__ base = xyz + (size_t)b * (NPTS * 3);

    __shared__ float4 xs4[CHUNKS], ys4[CHUNKS], zs4[CHUNKS];   // 48 KB
    __shared__ u64 redK[8];
    __shared__ int farbox;
    __shared__ float cxbox, cybox, czbox;

    // ---- transpose own points into LDS (thread-owned; published by the
    // first iteration's barrier 1 before any cross-thread read) ----
    float dist[4 * CPT];
#pragma unroll
    for (int j = 0; j < CPT; ++j) {
        const int c = t + j * THR;
        const float4* __restrict__ g4 =
            reinterpret_cast<const float4*>(base) + 3 * (me * CHUNKS + c);
        const float4 q0 = g4[0];
        const float4 q1 = g4[1];
        const float4 q2 = g4[2];
        xs4[c] = make_float4(q0.x, q0.w, q1.z, q2.y);
        ys4[c] = make_float4(q0.y, q1.x, q1.w, q2.z);
        zs4[c] = make_float4(q0.z, q1.y, q2.x, q2.w);
        dist[4 * j + 0] = BIGF; dist[4 * j + 1] = BIGF;
        dist[4 * j + 2] = BIGF; dist[4 * j + 3] = BIGF;
    }

    int far = finit[b];
    // iteration-0 centroid via global load (once); later iterations get the
    // winner's coords through the mailbox.
    float cx = base[3 * far + 0];
    float cy = base[3 * far + 1];
    float cz = base[3 * far + 2];

    const int wid  = t >> 6;       // 0..7
    const int lane = t & 63;

    for (int it = 0; it < NFPS; ++it) {
        if (me == 0 && t == 0) cidx[b * NFPS + it] = far;  // record BEFORE update
        if (it == NFPS - 1) break;                          // last far never used

        float vmax = -1.0f;
        int   amax = 0;

#define PROC(K, PX, PY, PZ, GI)                               \
        {                                                     \
            float dx = (PX) - cx;                             \
            float dy = (PY) - cy;                             \
            float dz = (PZ) - cz;                             \
            float d  = dx * dx + dy * dy;                     \
            d = d + dz * dz;                                  \
            float dk = fminf(dist[K], d);                     \
            dist[K] = dk;                                     \
            if (dk > vmax) { vmax = dk; amax = (GI); }        \
        }

#pragma unroll
        for (int j = 0; j < CPT; ++j) {
            const int c  = t + j * THR;
            const float4 xv = xs4[c];
            const float4 yv = ys4[c];
            const float4 zv = zs4[c];
            const int gi = me * PPB + 4 * c;
            PROC(4 * j + 0, xv.x, yv.x, zv.x, gi + 0);
            PROC(4 * j + 1, xv.y, yv.y, zv.y, gi + 1);
            PROC(4 * j + 2, xv.z, yv.z, zv.z, gi + 2);
            PROC(4 * j + 3, xv.w, yv.w, zv.w, gi + 3);
        }
#undef PROC

        // u64 key: high=distbits (>=0, order-monotone), low=~idx
        u64 key = ((u64)__float_as_uint(vmax) << 32)
                | (unsigned)(0xFFFFFFFFu - (unsigned)amax);
#pragma unroll
        for (int off = 32; off >= 1; off >>= 1) {
            u64 o = shfl_xor_u64(key, off);
            key = (o > key) ? o : key;
        }
        if (lane == 0) redK[wid] = key;
        __syncthreads();                       // barrier 1: redK published

        if (wid == 0) {
            u64 blockKey = redK[0];
#pragma unroll
            for (int w = 1; w < 8; ++w) {
                u64 o = redK[w];
                blockKey = (o > blockKey) ? o : blockKey;
            }
            const int gidx = (int)(0xFFFFFFFFu - (unsigned)(blockKey & 0xFFFFFFFFull));
            const int li   = gidx - me * PPB;           // in [0, PPB)
            const float candX = reinterpret_cast<const float*>(xs4)[li];
            const float candY = reinterpret_cast<const float*>(ys4)[li];
            const float candZ = reinterpret_cast<const float*>(zs4)[li];

            const u64 slotRow = mailAddr + (u64)((it * NBATCH + b) * P) * SLOTB;
            if (lane == 0) {
                v4u A; v2u B;
                A.x = (unsigned)(blockKey & 0xFFFFFFFFull);   // ~idx
                A.y = (unsigned)(blockKey >> 32);             // distbits
                A.z = __float_as_uint(candX);
                A.w = __float_as_uint(candY);
                B.x = A.x;
                B.y = __float_as_uint(candZ);
                mail_store(slotRow + (u64)me * SLOTB, A, B);
            }

            // lane-parallel poll: lane q owns slot q (q<8)
            u64   k  = 0;
            float px = candX, py = candY, pz = candZ;
            if (lane < P) {
                if (lane == me) {
                    k = blockKey;
                } else {
                    const u64 a = slotRow + (u64)lane * SLOTB;
                    v4u A; v2u B;
                    int fr = FROUNDS;
                    for (;;) {
                        if (fr > 0) { mail_loadF(a, &A, &B); --fr; }
                        else        { mail_loadS(a, &A, &B); }
                        if (msg_valid(A, B)) break;
                    }
                    k  = ((u64)A.y << 32) | A.x;
                    px = __uint_as_float(A.z);
                    py = __uint_as_float(A.w);
                    pz = __uint_as_float(B.y);
                }
            }
            // reduce (k, px,py,pz) across lanes 0..7 (offsets 4,2,1 keep
            // lanes 0-7 closed under xor; lanes >=8 hold k=0, never win)
#pragma unroll
            for (int off = 4; off >= 1; off >>= 1) {
                const u64   ok = shfl_xor_u64(k, off);
                const float ox = __shfl_xor(px, off, 64);
                const float oy = __shfl_xor(py, off, 64);
                const float oz = __shfl_xor(pz, off, 64);
                if (ok > k) { k = ok; px = ox; py = oy; pz = oz; }
            }
            if (lane == 0) {
                farbox = (int)(0xFFFFFFFFu - (unsigned)(k & 0xFFFFFFFFull));
                cxbox = px; cybox = py; czbox = pz;
            }
        }
        __syncthreads();                       // barrier 2: winner published
        far = farbox;
        cx = cxbox; cy = cybox; cz = czbox;
    }
}

// ---------------------------------------------------------------------------
// Ball query + grouping: QPB centroids per block (unchanged from R8-R12).
// ---------------------------------------------------------------------------
__global__ __launch_bounds__(256) void ballq_kernel(
    const float* __restrict__ xyz,
    const int* __restrict__ cidx,
    float* __restrict__ out0,      // [B][S][33][3]
    float* __restrict__ out1)      // [B][S][3]
{
#pragma clang fp contract(off)
    const int blk0 = blockIdx.x * QPB;   // first global centroid (b*NFPS+s)
    const int b    = blk0 >> 9;          // QPB divides NFPS -> same batch
    const int t    = threadIdx.x;
    const float* __restrict__ base = xyz + (size_t)b * (NPTS * 3);

    __shared__ u64 list[QPB][CAP];
    __shared__ int scnt[QPB];
    __shared__ u64 mask0[QPB];
    __shared__ int selIdx[QPB][NGRP];

    if (t < QPB) scnt[t] = 0;

    float cxs[QPB], cys[QPB], czs[QPB];
#pragma unroll
    for (int q = 0; q < QPB; ++q) {
        const int ci = cidx[blk0 + q];
        cxs[q] = base[3 * ci + 0];
        cys[q] = base[3 * ci + 1];
        czs[q] = base[3 * ci + 2];
    }
    __syncthreads();

    // in-ball masks for the first 64 indices (fill candidates); wave 0 only
    if (t < 64) {
        const float px = base[3 * t + 0];
        const float py = base[3 * t + 1];
        const float pz = base[3 * t + 2];
#pragma unroll
        for (int q = 0; q < QPB; ++q) {
            float dx = px - cxs[q];
            float dy = py - cys[q];
            float dz = pz - czs[q];
            float d  = dx * dx + dy * dy;
            d = d + dz * dz;
            u64 mk = __ballot(d <= R2F);
            if (t == 0) mask0[q] = mk;
        }
    }

    // scan all points once; test against all QPB centroids
    for (int k = 0; k < NPTS / 256; ++k) {
        const int p = k * 256 + t;
        const float px = base[3 * p + 0];
        const float py = base[3 * p + 1];
        const float pz = base[3 * p + 2];
#pragma unroll
        for (int q = 0; q < QPB; ++q) {
            float dx = px - cxs[q];
            float dy = py - cys[q];
            float dz = pz - czs[q];
            float d  = dx * dx + dy * dy;
            d = d + dz * dz;
            if (d <= R2F) {
                int pos = atomicAdd(&scnt[q], 1);
                if (pos < CAP)
                    list[q][pos] = (((u64)__float_as_uint(d)) << 32)
                                   | (unsigned)p;
            }
        }
    }
    __syncthreads();

    // rank-based selection, one wave per centroid:
    // key's rank == #smaller keys (keys unique via idx)
    {
        const int q    = t >> 6;     // wave id 0..3
        const int lane = t & 63;
        const int m = min(scnt[q], CAP);
        for (int j = lane; j < m; j += 64) {
            const u64 kj = list[q][j];
            int rank = 0;
            for (int i = 0; i < m; ++i) rank += (list[q][i] < kj) ? 1 : 0;
            if (rank < NGRP) selIdx[q][rank] = (int)(kj & 0xffffffffu);
        }
    }
    __syncthreads();

    if (t < 33 * QPB) {
        const int q    = t / 33;
        const int slot = t % 33;
        const int sg   = blk0 + q;
        const float cx = cxs[q], cy = cys[q], cz = czs[q];
        const size_t o0 = (size_t)sg * 33 * 3;
        if (slot == 32) {
            out0[o0 + 0] = cx; out0[o0 + 1] = cy; out0[o0 + 2] = cz;
            const size_t o1 = (size_t)sg * 3;
            out1[o1 + 0] = cx; out1[o1 + 1] = cy; out1[o1 + 2] = cz;
        } else {
            const int m = min(scnt[q], CAP);
            const int K = min(m, NGRP);
            int idx;
            if (slot < K) {
                idx = selIdx[q][slot];
            } else {
                // (slot-K+1)-th zero bit of mask0 = next out-of-radius index
                u64 zeros = ~mask0[q];
                const int need = slot - K;
                for (int z = 0; z < need; ++z) zeros &= zeros - 1;
                idx = __builtin_ctzll(zeros);
            }
            const float px = base[3 * idx + 0];
            const float py = base[3 * idx + 1];
            const float pz = base[3 * idx + 2];
            out0[o0 + (size_t)(1 + slot) * 3 + 0] = px - cx;
            out0[o0 + (size_t)(1 + slot) * 3 + 1] = py - cy;
            out0[o0 + (size_t)(1 + slot) * 3 + 2] = pz - cz;
        }
    }
}

extern "C" void kernel_launch(void* const* d_in, const int* in_sizes, int n_in,
                              void* d_out, int out_size, void* d_ws, size_t ws_size,
                              hipStream_t stream) {
    const float* xyz   = (const float*)d_in[0];
    const int*   finit = (const int*)d_in[1];
    float* out0 = (float*)d_out;
    float* out1 = out0 + (size_t)NBATCH * NFPS * 33 * 3;

    // ws layout: cidx 16 KB | mail (NFPS-1)*8*8*32 B = 1.0465 MB
    // total 1.0628 MB <= proven available (R9/R10 used this exact layout).
    int* cidx = (int*)d_ws;
    u64  mailAddr = (u64)(uintptr_t)((char*)d_ws
                   + (size_t)NBATCH * NFPS * sizeof(int));

    fps_kernel<<<NBATCH * P, THR, 0, stream>>>(xyz, finit, cidx, mailAddr);
    ballq_kernel<<<(NBATCH * NFPS) / QPB, 256, 0, stream>>>(xyz, cidx, out0, out1);
}

// Round 14
// 1270.092 us; speedup vs baseline: 1.9507x; 1.3248x over previous
//
#include <hip/hip_runtime.h>
#include <stdint.h>

#define NPTS   32768
#define NBATCH 8
#define NFPS   512
#define NGRP   32
#define BIGF   1e10f
#define R2F    0.04f
#define CAP    512
#define QPB    8      // ball-query centroids per block

// FPS decomposition
#define P      8                  // blocks per batch
#define PPB    (NPTS / P)         // 4096 points per block
#define CHUNKS (PPB / 4)          // 1024 float4-chunks per block
#define THR    1024               // threads per fps block (4 pts/thread)
#define SLOTB  32                 // bytes per mail slot

typedef unsigned long long u64;
typedef unsigned int v4u __attribute__((ext_vector_type(4)));
typedef unsigned int v2u __attribute__((ext_vector_type(2)));

__device__ __forceinline__ u64 shfl_xor_u64(u64 v, int off) {
    unsigned lo = (unsigned)v, hi = (unsigned)(v >> 32);
    lo = __shfl_xor(lo, off, 64);
    hi = __shfl_xor(hi, off, 64);
    return ((u64)hi << 32) | lo;
}

// Message A (16B, one transaction): [w0=~idx, w1=distbits, w2=x, w3=y]
// Message B ( 8B, one transaction): [w0=A.w0, w1=z]
// Valid iff distbits MSB==0, ~idx in [0xFFFF8000,0xFFFFFFFF] (idx<32768),
// B.x==A.x. Rejects 0xAA poison, zeros, torn A-new/B-old (write-once slots).
// Prior-replay values are bit-identical -> benign (R7-R13, absmax 0.0).
__device__ __forceinline__ bool msg_valid(v4u A, v2u B) {
    return ((A.y >> 31) == 0) && (A.x >= 0xFFFF8000u) && (B.x == A.x);
}

// Store: one sc0+sc1 pair (R10's proven discipline; R13's plain-first
// duplicate stores regressed and falsified the same-XCD-L2 fast path).
__device__ __forceinline__ void mail_store(u64 addr, v4u A, v2u B) {
    asm volatile(
        "global_store_dwordx4 %0, %2, off sc0 sc1\n\t"
        "global_store_dwordx2 %1, %3, off sc0 sc1"
        :: "v"(addr), "v"(addr + 16), "v"(A), "v"(B) : "memory");
}
// R14: pure device-coherence-point polling from round 0. R13's controlled
// test showed sc0 rounds never detect (first miss caches a STALE line in
// the reader's local L2; later sc0 rounds re-hit it fast and uselessly) --
// every detection came from the sc1 phase, after ~FROUNDSx250cyc of dead
// time. Removing the sc0 phase removes that dead time from every poll.
__device__ __forceinline__ void mail_load(u64 addr, v4u* A, v2u* B) {
    asm volatile(
        "global_load_dwordx4 %0, %2, off sc0 sc1\n\t"
        "global_load_dwordx2 %1, %3, off sc0 sc1\n\t"
        "s_waitcnt vmcnt(0)"
        : "=v"(*A), "=v"(*B) : "v"(addr), "v"(addr + 16) : "memory");
}

// ---------------------------------------------------------------------------
// FPS: P=8 blocks per batch, points in LDS (48 KB, thread-owned), dist[4]
// in VGPRs (THR=1024: ~45 VGPRs demand, safely under the 64-reg wall the
// compiler pins for 1024-thread kernels -- no spill possible).
// Structure = R10 (best known): 2 barriers/iter, wave0 does the exchange
// (post + lane-parallel poll of 8 slots + winner reduce), broadcast via LDS
// boxes. R12 proved all-wave polling convoys wave0; keep wave0 unloaded.
// Distance math bit-exact vs reference: contract off, (dx^2+dy^2)+dz^2,
// fminf accumulate; key (distbits<<32 | ~idx): max dist, ties -> min index;
// per-thread strict '>' in ascending global order keeps first occurrence.
// ---------------------------------------------------------------------------
__global__ __launch_bounds__(THR) void fps_kernel(
    const float* __restrict__ xyz,
    const int* __restrict__ finit,
    int* __restrict__ cidx,        // [NBATCH][NFPS]
    u64 mailAddr)                  // mail[NFPS-1][NBATCH][P] slots of 32 B
{
#pragma clang fp contract(off)
    const int gb = blockIdx.x;
    const int b  = gb & 7;         // batch
    const int me = gb >> 3;        // sub-block within batch
    const int t  = threadIdx.x;
    const float* __restrict__ base = xyz + (size_t)b * (NPTS * 3);

    __shared__ float4 xs4[CHUNKS], ys4[CHUNKS], zs4[CHUNKS];   // 48 KB
    __shared__ u64 redK[16];
    __shared__ int farbox;
    __shared__ float cxbox, cybox, czbox;

    // ---- transpose own 4 points into LDS (thread-owned; published by the
    // first iteration's barrier 1 before any cross-thread read) ----
    float dist[4];
    {
        const int c = t;                       // one chunk per thread
        const float4* __restrict__ g4 =
            reinterpret_cast<const float4*>(base) + 3 * (me * CHUNKS + c);
        const float4 q0 = g4[0];
        const float4 q1 = g4[1];
        const float4 q2 = g4[2];
        xs4[c] = make_float4(q0.x, q0.w, q1.z, q2.y);
        ys4[c] = make_float4(q0.y, q1.x, q1.w, q2.z);
        zs4[c] = make_float4(q0.z, q1.y, q2.x, q2.w);
        dist[0] = BIGF; dist[1] = BIGF; dist[2] = BIGF; dist[3] = BIGF;
    }

    int far = finit[b];
    // iteration-0 centroid via global load (once); later iterations get the
    // winner's coords through the mailbox.
    float cx = base[3 * far + 0];
    float cy = base[3 * far + 1];
    float cz = base[3 * far + 2];

    const int wid  = t >> 6;       // 0..15
    const int lane = t & 63;

    for (int it = 0; it < NFPS; ++it) {
        if (me == 0 && t == 0) cidx[b * NFPS + it] = far;  // record BEFORE update
        if (it == NFPS - 1) break;                          // last far never used

        float vmax = -1.0f;
        int   amax = 0;

#define PROC(K, PX, PY, PZ, GI)                               \
        {                                                     \
            float dx = (PX) - cx;                             \
            float dy = (PY) - cy;                             \
            float dz = (PZ) - cz;                             \
            float d  = dx * dx + dy * dy;                     \
            d = d + dz * dz;                                  \
            float dk = fminf(dist[K], d);                     \
            dist[K] = dk;                                     \
            if (dk > vmax) { vmax = dk; amax = (GI); }        \
        }
        {
            const int c  = t;
            const float4 xv = xs4[c];
            const float4 yv = ys4[c];
            const float4 zv = zs4[c];
            const int gi = me * PPB + 4 * c;
            PROC(0, xv.x, yv.x, zv.x, gi + 0);
            PROC(1, xv.y, yv.y, zv.y, gi + 1);
            PROC(2, xv.z, yv.z, zv.z, gi + 2);
            PROC(3, xv.w, yv.w, zv.w, gi + 3);
        }
#undef PROC

        // u64 key: high=distbits (>=0, order-monotone), low=~idx
        u64 key = ((u64)__float_as_uint(vmax) << 32)
                | (unsigned)(0xFFFFFFFFu - (unsigned)amax);
#pragma unroll
        for (int off = 32; off >= 1; off >>= 1) {
            u64 o = shfl_xor_u64(key, off);
            key = (o > key) ? o : key;
        }
        if (lane == 0) redK[wid] = key;
        __syncthreads();                       // barrier 1: redK published

        if (wid == 0) {
            u64 blockKey = redK[0];
#pragma unroll
            for (int w = 1; w < 16; ++w) {
                u64 o = redK[w];
                blockKey = (o > blockKey) ? o : blockKey;
            }
            const int gidx = (int)(0xFFFFFFFFu - (unsigned)(blockKey & 0xFFFFFFFFull));
            const int li   = gidx - me * PPB;           // in [0, PPB)
            const float candX = reinterpret_cast<const float*>(xs4)[li];
            const float candY = reinterpret_cast<const float*>(ys4)[li];
            const float candZ = reinterpret_cast<const float*>(zs4)[li];

            const u64 slotRow = mailAddr + (u64)((it * NBATCH + b) * P) * SLOTB;
            if (lane == 0) {
                v4u A; v2u B;
                A.x = (unsigned)(blockKey & 0xFFFFFFFFull);   // ~idx
                A.y = (unsigned)(blockKey >> 32);             // distbits
                A.z = __float_as_uint(candX);
                A.w = __float_as_uint(candY);
                B.x = A.x;
                B.y = __float_as_uint(candZ);
                mail_store(slotRow + (u64)me * SLOTB, A, B);
            }

            // lane-parallel poll: lane q owns slot q (q<8); pure sc1 rounds
            u64   k  = 0;
            float px = candX, py = candY, pz = candZ;
            if (lane < P) {
                if (lane == me) {
                    k = blockKey;
                } else {
                    const u64 a = slotRow + (u64)lane * SLOTB;
                    v4u A; v2u B;
                    for (;;) {
                        mail_load(a, &A, &B);
                        if (msg_valid(A, B)) break;
                    }
                    k  = ((u64)A.y << 32) | A.x;
                    px = __uint_as_float(A.z);
                    py = __uint_as_float(A.w);
                    pz = __uint_as_float(B.y);
                }
            }
            // reduce (k, px,py,pz) across lanes 0..7 (xor-closed; lanes >=8
            // hold k=0 and never win)
#pragma unroll
            for (int off = 4; off >= 1; off >>= 1) {
                const u64   ok = shfl_xor_u64(k, off);
                const float ox = __shfl_xor(px, off, 64);
                const float oy = __shfl_xor(py, off, 64);
                const float oz = __shfl_xor(pz, off, 64);
                if (ok > k) { k = ok; px = ox; py = oy; pz = oz; }
            }
            if (lane == 0) {
                farbox = (int)(0xFFFFFFFFu - (unsigned)(k & 0xFFFFFFFFull));
                cxbox = px; cybox = py; czbox = pz;
            }
        }
        __syncthreads();                       // barrier 2: winner published
        far = farbox;
        cx = cxbox; cy = cybox; cz = czbox;
    }
}

// ---------------------------------------------------------------------------
// Ball query + grouping: QPB=8 centroids per block (stream amortized 2x vs
// R13). Rank-select loops 2 centroids per wave; output loops 264 slots.
// ---------------------------------------------------------------------------
__global__ __launch_bounds__(256) void ballq_kernel(
    const float* __restrict__ xyz,
    const int* __restrict__ cidx,
    float* __restrict__ out0,      // [B][S][33][3]
    float* __restrict__ out1)      // [B][S][3]
{
#pragma clang fp contract(off)
    const int blk0 = blockIdx.x * QPB;   // first global centroid (b*NFPS+s)
    const int b    = blk0 >> 9;          // QPB divides 512 -> same batch
    const int t    = threadIdx.x;
    const float* __restrict__ base = xyz + (size_t)b * (NPTS * 3);

    __shared__ u64 list[QPB][CAP];       // 32 KB
    __shared__ int scnt[QPB];
    __shared__ u64 mask0[QPB];
    __shared__ int selIdx[QPB][NGRP];

    if (t < QPB) scnt[t] = 0;

    float cxs[QPB], cys[QPB], czs[QPB];
#pragma unroll
    for (int q = 0; q < QPB; ++q) {
        const int ci = cidx[blk0 + q];
        cxs[q] = base[3 * ci + 0];
        cys[q] = base[3 * ci + 1];
        czs[q] = base[3 * ci + 2];
    }
    __syncthreads();

    // in-ball masks for the first 64 indices (fill candidates); wave 0 only
    if (t < 64) {
        const float px = base[3 * t + 0];
        const float py = base[3 * t + 1];
        const float pz = base[3 * t + 2];
#pragma unroll
        for (int q = 0; q < QPB; ++q) {
            float dx = px - cxs[q];
            float dy = py - cys[q];
            float dz = pz - czs[q];
            float d  = dx * dx + dy * dy;
            d = d + dz * dz;
            u64 mk = __ballot(d <= R2F);
            if (t == 0) mask0[q] = mk;
        }
    }

    // scan all points once; test against all QPB centroids
    for (int k = 0; k < NPTS / 256; ++k) {
        const int p = k * 256 + t;
        const float px = base[3 * p + 0];
        const float py = base[3 * p + 1];
        const float pz = base[3 * p + 2];
#pragma unroll
        for (int q = 0; q < QPB; ++q) {
            float dx = px - cxs[q];
            float dy = py - cys[q];
            float dz = pz - czs[q];
            float d  = dx * dx + dy * dy;
            d = d + dz * dz;
            if (d <= R2F) {
                int pos = atomicAdd(&scnt[q], 1);
                if (pos < CAP)
                    list[q][pos] = (((u64)__float_as_uint(d)) << 32)
                                   | (unsigned)p;
            }
        }
    }
    __syncthreads();

    // rank-based selection, one wave per centroid, 2 centroids per wave:
    // key's rank == #smaller keys (keys unique via idx)
    {
        const int lane = t & 63;
        for (int q = t >> 6; q < QPB; q += 4) {
            const int m = min(scnt[q], CAP);
            for (int j = lane; j < m; j += 64) {
                const u64 kj = list[q][j];
                int rank = 0;
                for (int i = 0; i < m; ++i) rank += (list[q][i] < kj) ? 1 : 0;
                if (rank < NGRP) selIdx[q][rank] = (int)(kj & 0xffffffffu);
            }
        }
    }
    __syncthreads();

    for (int s = t; s < 33 * QPB; s += 256) {
        const int q    = s / 33;
        const int slot = s % 33;
        const int sg   = blk0 + q;
        const float cx = cxs[q], cy = cys[q], cz = czs[q];
        const size_t o0 = (size_t)sg * 33 * 3;
        if (slot == 32) {
            out0[o0 + 0] = cx; out0[o0 + 1] = cy; out0[o0 + 2] = cz;
            const size_t o1 = (size_t)sg * 3;
            out1[o1 + 0] = cx; out1[o1 + 1] = cy; out1[o1 + 2] = cz;
        } else {
            const int m = min(scnt[q], CAP);
            const int K = min(m, NGRP);
            int idx;
            if (slot < K) {
                idx = selIdx[q][slot];
            } else {
                // (slot-K+1)-th zero bit of mask0 = next out-of-radius index
                u64 zeros = ~mask0[q];
                const int need = slot - K;
                for (int z = 0; z < need; ++z) zeros &= zeros - 1;
                idx = __builtin_ctzll(zeros);
            }
            const float px = base[3 * idx + 0];
            const float py = base[3 * idx + 1];
            const float pz = base[3 * idx + 2];
            out0[o0 + (size_t)(1 + slot) * 3 + 0] = px - cx;
            out0[o0 + (size_t)(1 + slot) * 3 + 1] = py - cy;
            out0[o0 + (size_t)(1 + slot) * 3 + 2] = pz - cz;
        }
    }
}

extern "C" void kernel_launch(void* const* d_in, const int* in_sizes, int n_in,
                              void* d_out, int out_size, void* d_ws, size_t ws_size,
                              hipStream_t stream) {
    const float* xyz   = (const float*)d_in[0];
    const int*   finit = (const int*)d_in[1];
    float* out0 = (float*)d_out;
    float* out1 = out0 + (size_t)NBATCH * NFPS * 33 * 3;

    // ws layout: cidx 16 KB | mail (NFPS-1)*8*8*32 B = 1.0465 MB
    // total 1.0628 MB <= proven available (R9/R10/R13 used this layout).
    int* cidx = (int*)d_ws;
    u64  mailAddr = (u64)(uintptr_t)((char*)d_ws
                   + (size_t)NBATCH * NFPS * sizeof(int));

    fps_kernel<<<NBATCH * P, THR, 0, stream>>>(xyz, finit, cidx, mailAddr);
    ballq_kernel<<<(NBATCH * NFPS) / QPB, 256, 0, stream>>>(xyz, cidx, out0, out1);
}

// Round 17
// 1238.454 us; speedup vs baseline: 2.0005x; 1.0255x over previous
//
#include <hip/hip_runtime.h>
#include <stdint.h>

#define NPTS   32768
#define NBATCH 8
#define NFPS   512
#define NGRP   32
#define BIGF   1e10f
#define R2F    0.04f
#define CAP    512
#define QPB    8      // ball-query centroids per block

// FPS decomposition
#define P      8                  // blocks per batch
#define PPB    (NPTS / P)         // 4096 points per block
#define CHUNKS (PPB / 4)          // 1024 float4-chunks per block
#define THR    1024               // threads per fps block (4 pts/thread)
#define SLOTB  32                 // bytes per mail slot

typedef unsigned long long u64;
typedef unsigned int v4u __attribute__((ext_vector_type(4)));
typedef unsigned int v2u __attribute__((ext_vector_type(2)));

__device__ __forceinline__ u64 shfl_xor_u64(u64 v, int off) {
    unsigned lo = (unsigned)v, hi = (unsigned)(v >> 32);
    lo = __shfl_xor(lo, off, 64);
    hi = __shfl_xor(hi, off, 64);
    return ((u64)hi << 32) | lo;
}

// Message A (16B, one transaction): [w0=~idx, w1=distbits, w2=x, w3=y]
// Message B ( 8B, one transaction): [w0=A.w0, w1=z]
// Valid iff distbits MSB==0, ~idx in [0xFFFF8000,0xFFFFFFFF] (idx<32768),
// B.x==A.x. Rejects 0xAA poison, zeros, torn A-new/B-old (write-once slots).
// Prior-replay values are bit-identical -> benign (R7-R14, absmax 0.0).
__device__ __forceinline__ bool msg_valid(v4u A, v2u B) {
    return ((A.y >> 31) == 0) && (A.x >= 0xFFFF8000u) && (B.x == A.x);
}

// R14's proven store/load discipline: pure device-coherence-point (sc0 sc1)
// traffic; each poll round is a COMPLETE load->vmcnt(0)->check (no pipelined
// waitcnt choreography -- R15's depth-2 scheme is the suspected GPU hang).
__device__ __forceinline__ void mail_store(u64 addr, v4u A, v2u B) {
    asm volatile(
        "global_store_dwordx4 %0, %2, off sc0 sc1\n\t"
        "global_store_dwordx2 %1, %3, off sc0 sc1"
        :: "v"(addr), "v"(addr + 16), "v"(A), "v"(B) : "memory");
}
__device__ __forceinline__ void mail_load(u64 addr, v4u* A, v2u* B) {
    asm volatile(
        "global_load_dwordx4 %0, %2, off sc0 sc1\n\t"
        "global_load_dwordx2 %1, %3, off sc0 sc1\n\t"
        "s_waitcnt vmcnt(0)"
        : "=v"(*A), "=v"(*B) : "v"(addr), "v"(addr + 16) : "memory");
}

// ---------------------------------------------------------------------------
// FPS: P=8 blocks per batch, THR=1024, 4 pts/thread. Structure = R14 (best
// proven: 2.26us/iter, fps 1157us, total 1270us) with ONE delta: coords
// xr/yr/zr[4] in asm-pinned registers (12 regs, ~36 total -- far under the
// 64-reg wall; pin blocks R5/R6 remat) -> hot loop is pure VALU, no
// ds_read. LDS copy retained only for wave0's candidate lookup.
// R16 submitted this exact kernel and the CONTAINER failed -- consistent
// with R15's hang wedging the node, not with any mechanism here (poll loop
// is R14's proven complete-round spin; writer posts before polling; R6 ran
// the asm pin without issue). Resubmitting to disambiguate infra vs kernel.
// Distance math bit-exact vs reference: contract off, (dx^2+dy^2)+dz^2,
// fminf accumulate; key (distbits<<32 | ~idx): max dist, ties -> min index;
// per-thread strict '>' in ascending global order keeps first occurrence.
// ---------------------------------------------------------------------------
__global__ __launch_bounds__(THR) void fps_kernel(
    const float* __restrict__ xyz,
    const int* __restrict__ finit,
    int* __restrict__ cidx,        // [NBATCH][NFPS]
    u64 mailAddr)                  // mail[NFPS-1][NBATCH][P] slots of 32 B
{
#pragma clang fp contract(off)
    const int gb = blockIdx.x;
    const int b  = gb & 7;         // batch
    const int me = gb >> 3;        // sub-block within batch
    const int t  = threadIdx.x;
    const float* __restrict__ base = xyz + (size_t)b * (NPTS * 3);

    __shared__ float4 xs4[CHUNKS], ys4[CHUNKS], zs4[CHUNKS];   // 48 KB
    __shared__ u64 redK[16];
    __shared__ int farbox;
    __shared__ float cxbox, cybox, czbox;

    // ---- load own 4 points into registers AND into LDS (LDS copy only for
    // wave0's candidate lookup; published by iteration 0's barrier 1) ----
    float xr[4], yr[4], zr[4], dist[4];
    {
        const float4* __restrict__ g4 =
            reinterpret_cast<const float4*>(base) + 3 * (me * CHUNKS + t);
        const float4 q0 = g4[0];
        const float4 q1 = g4[1];
        const float4 q2 = g4[2];
        xr[0] = q0.x; yr[0] = q0.y; zr[0] = q0.z;
        xr[1] = q0.w; yr[1] = q1.x; zr[1] = q1.y;
        xr[2] = q1.z; yr[2] = q1.w; zr[2] = q2.x;
        xr[3] = q2.y; yr[3] = q2.z; zr[3] = q2.w;
        xs4[t] = make_float4(xr[0], xr[1], xr[2], xr[3]);
        ys4[t] = make_float4(yr[0], yr[1], yr[2], yr[3]);
        zs4[t] = make_float4(zr[0], zr[1], zr[2], zr[3]);
        dist[0] = BIGF; dist[1] = BIGF; dist[2] = BIGF; dist[3] = BIGF;
    }
    // pin coords into live VGPRs (R5/R6 lesson: the allocator remats loads
    // of read-only data; an asm result cannot be rematerialized)
#pragma unroll
    for (int k = 0; k < 4; ++k) {
        asm("" : "+v"(xr[k]), "+v"(yr[k]), "+v"(zr[k]));
    }

    int far = finit[b];
    // iteration-0 centroid via global load (once); later iterations get the
    // winner's coords through the mailbox.
    float cx = base[3 * far + 0];
    float cy = base[3 * far + 1];
    float cz = base[3 * far + 2];

    const int wid  = t >> 6;       // 0..15
    const int lane = t & 63;

    for (int it = 0; it < NFPS; ++it) {
        if (me == 0 && t == 0) cidx[b * NFPS + it] = far;  // record BEFORE update
        if (it == NFPS - 1) break;                          // last far never used

        float vmax = -1.0f;
        int   amax = 0;
        const int gi = me * PPB + 4 * t;
#pragma unroll
        for (int k = 0; k < 4; ++k) {
            float dx = xr[k] - cx;
            float dy = yr[k] - cy;
            float dz = zr[k] - cz;
            float d  = dx * dx + dy * dy;
            d = d + dz * dz;
            float dk = fminf(dist[k], d);
            dist[k] = dk;
            if (dk > vmax) { vmax = dk; amax = gi + k; }
        }

        // u64 key: high=distbits (>=0, order-monotone), low=~idx
        u64 key = ((u64)__float_as_uint(vmax) << 32)
                | (unsigned)(0xFFFFFFFFu - (unsigned)amax);
#pragma unroll
        for (int off = 32; off >= 1; off >>= 1) {
            u64 o = shfl_xor_u64(key, off);
            key = (o > key) ? o : key;
        }
        if (lane == 0) redK[wid] = key;
        __syncthreads();                       // barrier 1: redK published

        if (wid == 0) {
            u64 blockKey = redK[0];
#pragma unroll
            for (int w = 1; w < 16; ++w) {
                u64 o = redK[w];
                blockKey = (o > blockKey) ? o : blockKey;
            }
            const int gidx = (int)(0xFFFFFFFFu - (unsigned)(blockKey & 0xFFFFFFFFull));
            const int li   = gidx - me * PPB;           // in [0, PPB)
            const float candX = reinterpret_cast<const float*>(xs4)[li];
            const float candY = reinterpret_cast<const float*>(ys4)[li];
            const float candZ = reinterpret_cast<const float*>(zs4)[li];

            const u64 slotRow = mailAddr + (u64)((it * NBATCH + b) * P) * SLOTB;
            if (lane == 0) {
                v4u A; v2u B;
                A.x = (unsigned)(blockKey & 0xFFFFFFFFull);   // ~idx
                A.y = (unsigned)(blockKey >> 32);             // distbits
                A.z = __float_as_uint(candX);
                A.w = __float_as_uint(candY);
                B.x = A.x;
                B.y = __float_as_uint(candZ);
                mail_store(slotRow + (u64)me * SLOTB, A, B);
            }

            // lane-parallel poll: lane q owns slot q (q<8); simple sc1 rounds
            u64   k  = 0;
            float px = candX, py = candY, pz = candZ;
            if (lane < P) {
                if (lane == me) {
                    k = blockKey;
                } else {
                    const u64 a = slotRow + (u64)lane * SLOTB;
                    v4u A; v2u B;
                    for (;;) {
                        mail_load(a, &A, &B);
                        if (msg_valid(A, B)) break;
                    }
                    k  = ((u64)A.y << 32) | A.x;
                    px = __uint_as_float(A.z);
                    py = __uint_as_float(A.w);
                    pz = __uint_as_float(B.y);
                }
            }
            // reduce (k, px,py,pz) across lanes 0..7 (xor-closed; lanes >=8
            // hold k=0 and never win)
#pragma unroll
            for (int off = 4; off >= 1; off >>= 1) {
                const u64   ok = shfl_xor_u64(k, off);
                const float ox = __shfl_xor(px, off, 64);
                const float oy = __shfl_xor(py, off, 64);
                const float oz = __shfl_xor(pz, off, 64);
                if (ok > k) { k = ok; px = ox; py = oy; pz = oz; }
            }
            if (lane == 0) {
                farbox = (int)(0xFFFFFFFFu - (unsigned)(k & 0xFFFFFFFFull));
                cxbox = px; cybox = py; czbox = pz;
            }
        }
        __syncthreads();                       // barrier 2: winner published
        far = farbox;
        cx = cxbox; cy = cybox; cz = czbox;
    }
}

// ---------------------------------------------------------------------------
// Ball query + grouping: QPB=8 centroids per block (unchanged from R14).
// ---------------------------------------------------------------------------
__global__ __launch_bounds__(256) void ballq_kernel(
    const float* __restrict__ xyz,
    const int* __restrict__ cidx,
    float* __restrict__ out0,      // [B][S][33][3]
    float* __restrict__ out1)      // [B][S][3]
{
#pragma clang fp contract(off)
    const int blk0 = blockIdx.x * QPB;   // first global centroid (b*NFPS+s)
    const int b    = blk0 >> 9;          // QPB divides 512 -> same batch
    const int t    = threadIdx.x;
    const float* __restrict__ base = xyz + (size_t)b * (NPTS * 3);

    __shared__ u64 list[QPB][CAP];       // 32 KB
    __shared__ int scnt[QPB];
    __shared__ u64 mask0[QPB];
    __shared__ int selIdx[QPB][NGRP];

    if (t < QPB) scnt[t] = 0;

    float cxs[QPB], cys[QPB], czs[QPB];
#pragma unroll
    for (int q = 0; q < QPB; ++q) {
        const int ci = cidx[blk0 + q];
        cxs[q] = base[3 * ci + 0];
        cys[q] = base[3 * ci + 1];
        czs[q] = base[3 * ci + 2];
    }
    __syncthreads();

    // in-ball masks for the first 64 indices (fill candidates); wave 0 only
    if (t < 64) {
        const float px = base[3 * t + 0];
        const float py = base[3 * t + 1];
        const float pz = base[3 * t + 2];
#pragma unroll
        for (int q = 0; q < QPB; ++q) {
            float dx = px - cxs[q];
            float dy = py - cys[q];
            float dz = pz - czs[q];
            float d  = dx * dx + dy * dy;
            d = d + dz * dz;
            u64 mk = __ballot(d <= R2F);
            if (t == 0) mask0[q] = mk;
        }
    }

    // scan all points once; test against all QPB centroids
    for (int k = 0; k < NPTS / 256; ++k) {
        const int p = k * 256 + t;
        const float px = base[3 * p + 0];
        const float py = base[3 * p + 1];
        const float pz = base[3 * p + 2];
#pragma unroll
        for (int q = 0; q < QPB; ++q) {
            float dx = px - cxs[q];
            float dy = py - cys[q];
            float dz = pz - czs[q];
            float d  = dx * dx + dy * dy;
            d = d + dz * dz;
            if (d <= R2F) {
                int pos = atomicAdd(&scnt[q], 1);
                if (pos < CAP)
                    list[q][pos] = (((u64)__float_as_uint(d)) << 32)
                                   | (unsigned)p;
            }
        }
    }
    __syncthreads();

    // rank-based selection, 2 centroids per wave:
    // key's rank == #smaller keys (keys unique via idx)
    {
        const int lane = t & 63;
        for (int q = t >> 6; q < QPB; q += 4) {
            const int m = min(scnt[q], CAP);
            for (int j = lane; j < m; j += 64) {
                const u64 kj = list[q][j];
                int rank = 0;
                for (int i = 0; i < m; ++i) rank += (list[q][i] < kj) ? 1 : 0;
                if (rank < NGRP) selIdx[q][rank] = (int)(kj & 0xffffffffu);
            }
        }
    }
    __syncthreads();

    for (int s = t; s < 33 * QPB; s += 256) {
        const int q    = s / 33;
        const int slot = s % 33;
        const int sg   = blk0 + q;
        const float cx = cxs[q], cy = cys[q], cz = czs[q];
        const size_t o0 = (size_t)sg * 33 * 3;
        if (slot == 32) {
            out0[o0 + 0] = cx; out0[o0 + 1] = cy; out0[o0 + 2] = cz;
            const size_t o1 = (size_t)sg * 3;
            out1[o1 + 0] = cx; out1[o1 + 1] = cy; out1[o1 + 2] = cz;
        } else {
            const int m = min(scnt[q], CAP);
            const int K = min(m, NGRP);
            int idx;
            if (slot < K) {
                idx = selIdx[q][slot];
            } else {
                // (slot-K+1)-th zero bit of mask0 = next out-of-radius index
                u64 zeros = ~mask0[q];
                const int need = slot - K;
                for (int z = 0; z < need; ++z) zeros &= zeros - 1;
                idx = __builtin_ctzll(zeros);
            }
            const float px = base[3 * idx + 0];
            const float py = base[3 * idx + 1];
            const float pz = base[3 * idx + 2];
            out0[o0 + (size_t)(1 + slot) * 3 + 0] = px - cx;
            out0[o0 + (size_t)(1 + slot) * 3 + 1] = py - cy;
            out0[o0 + (size_t)(1 + slot) * 3 + 2] = pz - cz;
        }
    }
}

extern "C" void kernel_launch(void* const* d_in, const int* in_sizes, int n_in,
                              void* d_out, int out_size, void* d_ws, size_t ws_size,
                              hipStream_t stream) {
    const float* xyz   = (const float*)d_in[0];
    const int*   finit = (const int*)d_in[1];
    float* out0 = (float*)d_out;
    float* out1 = out0 + (size_t)NBATCH * NFPS * 33 * 3;

    // ws layout: cidx 16 KB | mail (NFPS-1)*8*8*32 B = 1.0465 MB
    // total 1.0628 MB <= proven available (R9/R10/R13/R14 used this layout).
    int* cidx = (int*)d_ws;
    u64  mailAddr = (u64)(uintptr_t)((char*)d_ws
                   + (size_t)NBATCH * NFPS * sizeof(int));

    fps_kernel<<<NBATCH * P, THR, 0, stream>>>(xyz, finit, cidx, mailAddr);
    ballq_kernel<<<(NBATCH * NFPS) / QPB, 256, 0, stream>>>(xyz, cidx, out0, out1);
}